// Round 2
// baseline (765.663 us; speedup 1.0000x reference)
//
#include <hip/hip_runtime.h>
#include <stdint.h>

// TrajEncoder: embedding gather + LSTM(D=128,H=256) over T=512, output h at valid_len-1.
// Design: 64 clusters (one per batch) x 4 WGs; each WG owns 64 hidden units (256 gate
// rows), W_hh/W_ih slices live f16-packed in registers. Per step: dot2-GEMV + pointwise
// LSTM update; cluster exchanges h slices through d_ws using agent-scope atomics with
// epoch-encoded values (phase0: h in (-1,1); phase1: h+8) -> consumers spin on data
// words directly, one L3 RTT per step, no flags/fences needed.

#define BB 64
#define TT 512
#define DD 128
#define HH 256

typedef __fp16 half2v __attribute__((ext_vector_type(2)));

__device__ __forceinline__ uint32_t pk_f16(float lo, float hi) {
    half2v h = __builtin_amdgcn_cvt_pkrtz(lo, hi);
    return __builtin_bit_cast(uint32_t, h);
}

__device__ __forceinline__ float dot2(uint32_t a, uint32_t b, float acc) {
#if __has_builtin(__builtin_amdgcn_fdot2)
    return __builtin_amdgcn_fdot2(__builtin_bit_cast(half2v, a),
                                  __builtin_bit_cast(half2v, b), acc, false);
#else
    half2v av = __builtin_bit_cast(half2v, a);
    half2v bv = __builtin_bit_cast(half2v, b);
    acc += (float)av[0] * (float)bv[0];
    acc += (float)av[1] * (float)bv[1];
    return acc;
#endif
}

__device__ __forceinline__ float fsig(float x)  { return 1.f / (1.f + __expf(-x)); }
__device__ __forceinline__ float ftanh(float x) { return 1.f - 2.f / (__expf(2.f * x) + 1.f); }

__global__ __launch_bounds__(1024, 4)
void lstm_cluster_kernel(const int* __restrict__ path, const int* __restrict__ vlen,
                         const float* __restrict__ emb, const float* __restrict__ Wih,
                         const float* __restrict__ Whh, const float* __restrict__ bih,
                         const float* __restrict__ bhh, float* __restrict__ out,
                         float* hslot /* [2][BB][HH] exchange buffer in ws */) {
    const int b   = blockIdx.x & (BB - 1);
    const int k   = blockIdx.x >> 6;      // cluster member 0..3: owns h units [64k,64k+64)
    const int tid = threadIdx.x;
    const int r   = tid >> 2;             // local gate row 0..255
    const int q   = tid & 3;              // K-quarter
    const int g   = r >> 6;               // gate type: 0=i 1=f 2=g 3=o
    const int u   = r & 63;               // unit within slice
    const int grow = (g << 8) + (k << 6) + u;   // global gate row in [0,1024)

    __shared__ uint32_t h_pk[4][40];      // f16x2 h, per K-quarter (32 used + pad: bank-stagger)
    __shared__ uint32_t x_pk[2][4][24];   // f16x2 x_t, double buffered (16 used + pad)
    __shared__ float    G[256];           // gate pre-activations
    __shared__ int      path_l[TT];

    // ---- preload weight slices into registers as packed f16 pairs ----
    uint32_t whh[32];
    {
        const float* wr = Whh + grow * HH + (q << 6);
#pragma unroll
        for (int c = 0; c < 32; ++c) whh[c] = pk_f16(wr[2 * c], wr[2 * c + 1]);
    }
    uint32_t wih[16];
    {
        const float* wr = Wih + grow * DD + (q << 5);
#pragma unroll
        for (int c = 0; c < 16; ++c) wih[c] = pk_f16(wr[2 * c], wr[2 * c + 1]);
    }
    const float bias = bih[grow] + bhh[grow];
    const int   L    = vlen[b];

    if (tid < TT)  path_l[tid] = path[b * TT + tid];
    if (tid < 160) ((uint32_t*)h_pk)[tid] = 0u;   // h_0 = 0 (zeros incl. pads)
    __syncthreads();

    // stage x_0, prefetch x_1
    float xr_next = 0.f;
    if (tid < DD) {
        float x0 = emb[(size_t)path_l[0] * DD + tid];
        float hi = __shfl_xor(x0, 1);
        if (!(tid & 1)) x_pk[0][tid >> 5][(tid & 31) >> 1] = pk_f16(x0, hi);
        xr_next = emb[(size_t)path_l[L > 1 ? 1 : 0] * DD + tid];
    }
    float c_state = 0.f;
    __syncthreads();

    for (int t = 0; t < L; ++t) {
        const int slot  = t & 1;
        const int phase = (t >> 1) & 1;

        // (A) prefetch x_{t+2} (hides L3/HBM latency under this step)
        float xr_pf = 0.f;
        if (tid < DD) {
            int tpf = (t + 2 < TT) ? t + 2 : TT - 1;
            xr_pf = emb[(size_t)path_l[tpf] * DD + tid];
        }

        // (B) partial dots: this thread covers cols [64q,64q+64) of h, [32q,32q+32) of x
        float acc = 0.f;
#pragma unroll
        for (int c = 0; c < 8; ++c) {
            uint4 hv = *(const uint4*)&h_pk[q][c << 2];
            acc = dot2(whh[(c << 2) + 0], hv.x, acc);
            acc = dot2(whh[(c << 2) + 1], hv.y, acc);
            acc = dot2(whh[(c << 2) + 2], hv.z, acc);
            acc = dot2(whh[(c << 2) + 3], hv.w, acc);
        }
#pragma unroll
        for (int c = 0; c < 4; ++c) {
            uint4 xv = *(const uint4*)&x_pk[slot][q][c << 2];
            acc = dot2(wih[(c << 2) + 0], xv.x, acc);
            acc = dot2(wih[(c << 2) + 1], xv.y, acc);
            acc = dot2(wih[(c << 2) + 2], xv.z, acc);
            acc = dot2(wih[(c << 2) + 3], xv.w, acc);
        }

        // (C) reduce across the 4 K-quarters (lanes 4r..4r+3)
        acc += __shfl_xor(acc, 1);
        acc += __shfl_xor(acc, 2);
        if (q == 0) G[r] = acc + bias;
        __syncthreads();

        // (E) stage x_{t+1} to LDS; pointwise LSTM update on owned units; publish h slice
        if (tid < DD) {
            float hi = __shfl_xor(xr_next, 1);
            if (!(tid & 1)) x_pk[slot ^ 1][tid >> 5][(tid & 31) >> 1] = pk_f16(xr_next, hi);
        }
        if (tid < 64) {
            float gi = fsig(G[tid]);
            float gf = fsig(G[64 + tid]);
            float gg = ftanh(G[128 + tid]);
            float go = fsig(G[192 + tid]);
            c_state  = gf * c_state + gi * gg;
            float h  = go * ftanh(c_state);
            if (t == L - 1) out[b * HH + (k << 6) + tid] = h;
            __hip_atomic_store(&hslot[(slot * BB + b) * HH + (k << 6) + tid],
                               phase ? h + 8.f : h,
                               __ATOMIC_RELAXED, __HIP_MEMORY_SCOPE_AGENT);
        }
        xr_next = xr_pf;

        // (F) gather full h_{t+1}: spin on epoch-encoded values (|h|<1 strictly)
        if (t < L - 1) {
            if (tid < HH) {
                float* addr = &hslot[(slot * BB + b) * HH + tid];
                float v;
                int spins = 0;
                if (phase == 0) {
                    do { v = __hip_atomic_load(addr, __ATOMIC_RELAXED, __HIP_MEMORY_SCOPE_AGENT);
                    } while (!(v > -4.f && v < 4.f) && ++spins < 200000);
                } else {
                    do { v = __hip_atomic_load(addr, __ATOMIC_RELAXED, __HIP_MEMORY_SCOPE_AGENT);
                    } while (!(v > 4.f) && ++spins < 200000);
                    v -= 8.f;
                }
                float hi = __shfl_xor(v, 1);
                if (!(tid & 1)) h_pk[tid >> 6][(tid & 63) >> 1] = pk_f16(v, hi);
            }
        }
        __syncthreads();   // (G) h_pk / x_pk ready for next step
    }
}

extern "C" void kernel_launch(void* const* d_in, const int* in_sizes, int n_in,
                              void* d_out, int out_size, void* d_ws, size_t ws_size,
                              hipStream_t stream) {
    const int*   path = (const int*)d_in[0];
    const int*   vlen = (const int*)d_in[1];
    const float* emb  = (const float*)d_in[2];
    const float* Wih  = (const float*)d_in[3];
    const float* Whh  = (const float*)d_in[4];
    const float* bih  = (const float*)d_in[5];
    const float* bhh  = (const float*)d_in[6];

    // init exchange buffer to 0x41414141 (=12.08f): rejected by the phase-0 range
    // check, so steps 0/1 never consume stale data. Re-done every launch -> deterministic.
    (void)hipMemsetAsync(d_ws, 0x41, (size_t)2 * BB * HH * sizeof(float), stream);
    lstm_cluster_kernel<<<256, 1024, 0, stream>>>(path, vlen, emb, Wih, Whh, bih, bhh,
                                                  (float*)d_out, (float*)d_ws);
}

// Round 3
// 679.504 us; speedup vs baseline: 1.1268x; 1.1268x over previous
//
#include <hip/hip_runtime.h>
#include <stdint.h>

// TrajEncoder: embedding gather + LSTM(D=128,H=256) over T=512, output h at valid_len-1.
// 64 clusters (one per batch) x 4 WGs; each WG owns 64 hidden units (256 gate rows),
// weight slices f16-packed in registers. Per step: dot2-GEMV + pointwise update.
// Cluster h-exchange: packed f16x2 u32 through d_ws, epoch-encoded by bitwise NOT
// (h in (-1,1] => bit14 of each half clear; ~pk => bit14 set). Consumers are dedicated
// poller waves spinning with relaxed agent-scope loads; own slice goes via LDS only.

#define BB 64
#define TT 512
#define DD 128
#define HH 256

typedef __fp16 half2v __attribute__((ext_vector_type(2)));

__device__ __forceinline__ uint32_t pk_f16(float lo, float hi) {
    half2v h = __builtin_amdgcn_cvt_pkrtz(lo, hi);
    return __builtin_bit_cast(uint32_t, h);
}

__device__ __forceinline__ float dot2(uint32_t a, uint32_t b, float acc) {
#if __has_builtin(__builtin_amdgcn_fdot2)
    return __builtin_amdgcn_fdot2(__builtin_bit_cast(half2v, a),
                                  __builtin_bit_cast(half2v, b), acc, false);
#else
    half2v av = __builtin_bit_cast(half2v, a);
    half2v bv = __builtin_bit_cast(half2v, b);
    acc += (float)av[0] * (float)bv[0];
    acc += (float)av[1] * (float)bv[1];
    return acc;
#endif
}

__device__ __forceinline__ float fsig(float x)  { return 1.f / (1.f + __expf(-x)); }
__device__ __forceinline__ float ftanh(float x) { return 1.f - 2.f / (__expf(2.f * x) + 1.f); }

__global__ __launch_bounds__(1024, 4)
void lstm_cluster_kernel(const int* __restrict__ path, const int* __restrict__ vlen,
                         const float* __restrict__ emb, const float* __restrict__ Wih,
                         const float* __restrict__ Whh, const float* __restrict__ bih,
                         const float* __restrict__ bhh, float* __restrict__ out,
                         uint32_t* hx /* [2][BB][128] packed-u32 exchange in ws */) {
    const int b   = blockIdx.x & (BB - 1);
    const int k   = blockIdx.x >> 6;      // cluster member 0..3: owns h units [64k,64k+64)
    const int tid = threadIdx.x;
    const int r   = tid >> 2;             // local gate row 0..255
    const int q   = tid & 3;              // K-quarter
    const int g   = r >> 6;               // gate: 0=i 1=f 2=g 3=o
    const int u   = r & 63;
    const int grow = (g << 8) + (k << 6) + u;   // global gate row in [0,1024)

    __shared__ uint32_t h_pk[4][40];      // f16x2 h per K-quarter (32 used + pad)
    __shared__ uint32_t x_pk[2][4][24];   // f16x2 x_t, double buffered (16 used + pad)
    __shared__ float    G[256];           // gate pre-activations
    __shared__ int      path_l[TT];

    // ---- weight slices -> packed f16 registers ----
    uint32_t whh[32];
    {
        const float* wr = Whh + grow * HH + (q << 6);
#pragma unroll
        for (int c = 0; c < 32; ++c) whh[c] = pk_f16(wr[2 * c], wr[2 * c + 1]);
    }
    uint32_t wih[16];
    {
        const float* wr = Wih + grow * DD + (q << 5);
#pragma unroll
        for (int c = 0; c < 16; ++c) wih[c] = pk_f16(wr[2 * c], wr[2 * c + 1]);
    }
    const float bias = bih[grow] + bhh[grow];
    const int   L    = vlen[b];

    if (tid < TT)  path_l[tid] = path[b * TT + tid];
    if (tid < 160) ((uint32_t*)h_pk)[tid] = 0u;   // h_0 = 0
    __syncthreads();

    // waves 2-3 own the x pipeline: stage x_0, prefetch x_1
    float xr_next = 0.f;
    if (tid >= 128 && tid < 256) {
        int e = tid - 128;
        float x0 = emb[(size_t)path_l[0] * DD + e];
        float hi = __shfl_xor(x0, 1);
        if (!(e & 1)) x_pk[0][e >> 5][(e & 31) >> 1] = pk_f16(x0, hi);
        xr_next = emb[(size_t)path_l[L > 1 ? 1 : 0] * DD + e];
    }
    float c_state = 0.f;
    __syncthreads();

    for (int t = 0; t < L; ++t) {
        const int slot  = t & 1;
        const int phase = (t >> 1) & 1;
        const uint32_t want = phase ? 0x40004000u : 0u;

        // (B) partial dots: cols [64q,64q+64) of h, [32q,32q+32) of x
        float acc = 0.f;
#pragma unroll
        for (int c = 0; c < 8; ++c) {
            uint4 hv = *(const uint4*)&h_pk[q][c << 2];
            acc = dot2(whh[(c << 2) + 0], hv.x, acc);
            acc = dot2(whh[(c << 2) + 1], hv.y, acc);
            acc = dot2(whh[(c << 2) + 2], hv.z, acc);
            acc = dot2(whh[(c << 2) + 3], hv.w, acc);
        }
#pragma unroll
        for (int c = 0; c < 4; ++c) {
            uint4 xv = *(const uint4*)&x_pk[slot][q][c << 2];
            acc = dot2(wih[(c << 2) + 0], xv.x, acc);
            acc = dot2(wih[(c << 2) + 1], xv.y, acc);
            acc = dot2(wih[(c << 2) + 2], xv.z, acc);
            acc = dot2(wih[(c << 2) + 3], xv.w, acc);
        }
        // (C) reduce across the 4 K-quarters
        acc += __shfl_xor(acc, 1);
        acc += __shfl_xor(acc, 2);
        if (q == 0) G[r] = acc + bias;
        __syncthreads();

        // ---- role phase: wave0 pointwise+publish | waves2-3 x stage | waves14-15 poll ----
        if (tid < 64) {
            float gi = fsig(G[tid]);
            float gf = fsig(G[64 + tid]);
            float gg = ftanh(G[128 + tid]);
            float go = fsig(G[192 + tid]);
            c_state  = gf * c_state + gi * gg;
            float h  = go * ftanh(c_state);
            if (t == L - 1) out[b * HH + (k << 6) + tid] = h;
            float h1 = __shfl_xor(h, 1);
            if (!(tid & 1)) {
                uint32_t pk = pk_f16(h, h1);
                h_pk[k][tid >> 1] = pk;                       // own slice: LDS only
                __hip_atomic_store(&hx[(slot * BB + b) * 128 + (k << 5) + (tid >> 1)],
                                   phase ? ~pk : pk,
                                   __ATOMIC_RELAXED, __HIP_MEMORY_SCOPE_AGENT);
            }
        } else if (tid >= 128 && tid < 256) {
            int e = tid - 128;
            float hi = __shfl_xor(xr_next, 1);
            if (!(e & 1)) x_pk[slot ^ 1][e >> 5][(e & 31) >> 1] = pk_f16(xr_next, hi);
            int tpf = (t + 2 < TT) ? t + 2 : TT - 1;
            xr_next = emb[(size_t)path_l[tpf] * DD + e];      // prefetch x_{t+2}
        } else if (tid >= 896 && tid < 992 && t < L - 1) {
            int j  = tid - 896;                               // 96 remote u32s
            int qq = j >> 5; if (qq >= k) ++qq;               // skip own quarter
            int c  = j & 31;
            uint32_t* addr = &hx[(slot * BB + b) * 128 + (qq << 5) + c];
            uint32_t v; int spins = 0;
            do {
                v = __hip_atomic_load(addr, __ATOMIC_RELAXED, __HIP_MEMORY_SCOPE_AGENT);
            } while ((v & 0x40004000u) != want && ++spins < (1 << 20));
            h_pk[qq][c] = phase ? ~v : v;                     // decode = bitwise NOT
        }
        __syncthreads();   // h_pk / x_pk ready for next step
    }
}

extern "C" void kernel_launch(void* const* d_in, const int* in_sizes, int n_in,
                              void* d_out, int out_size, void* d_ws, size_t ws_size,
                              hipStream_t stream) {
    const int*   path = (const int*)d_in[0];
    const int*   vlen = (const int*)d_in[1];
    const float* emb  = (const float*)d_in[2];
    const float* Wih  = (const float*)d_in[3];
    const float* Whh  = (const float*)d_in[4];
    const float* bih  = (const float*)d_in[5];
    const float* bhh  = (const float*)d_in[6];

    // init exchange to 0xFFFFFFFF: bit14 set in both halves -> rejected by the
    // phase-0 predicate used at steps 0/1 (only steps that can see init data).
    (void)hipMemsetAsync(d_ws, 0xFF, (size_t)2 * BB * 128 * sizeof(uint32_t), stream);
    lstm_cluster_kernel<<<256, 1024, 0, stream>>>(path, vlen, emb, Wih, Whh, bih, bhh,
                                                  (float*)d_out, (uint32_t*)d_ws);
}